// Round 3
// baseline (1387.893 us; speedup 1.0000x reference)
//
#include <hip/hip_runtime.h>

// ---------------------------------------------------------------------------
// ElectrostaticFieldInteractionBlock — fp32 bisect build (no MFMA, no bf16).
//
// Reduction: M_k[t,v] = (1/sqrt(128)) * sum_u Wup[t,u]*tp_w[k][u]*Wl[uoff_k+u,v]
//   P_k[n,v]   = sum_t s[n,t]   M_k[t,v]   (k=0,1,2; Wup0)
//   Q_k[n,v,a] = sum_t v[n,t,a] M_k[t,v]   (k=3..6; Wup1)
// Outputs out[n,v,j], j=0..8 (strides: n*1152 + v*9 + j):
//   j0      = (a2/16) ( f0 P0 + (1/sqrt3) sum_a f1[a] Q4[a] )
//   j1..3,c = (1/(24 sqrt2)) ( (1/sqrt3)(f1[c] P1 + f0 Q3[c]) + sum_a g6[a][c] Q6[a] )
//   j4..8,c = (a2/16) ( (1/sqrt5) f2[c] P2 + sum_a g5[a][c] Q5[a] )
// g5[a][c] = sum_b C112[a,b,c] f1[b];  g6[a][c] = sum_b C112[a,c,b] f2[b]
// C112 (V=1/sqrt10, W=1/sqrt30; l1 basis (y,z,x), l2 basis (xy,yz,z2,xz,x2-y2)):
//   [0,2,xy]=[2,0,xy]=V; [0,1,yz]=[1,0,yz]=V; [1,2,xz]=[2,1,xz]=V;
//   [0,0,z2]=-W; [1,1,z2]=2W; [2,2,z2]=-W; [0,0,c4]=-V; [2,2,c4]=+V
// ---------------------------------------------------------------------------

// ------------------------- kernel 1: precompute M (fp32) --------------------
__global__ __launch_bounds__(256) void precompute_Mf(
    const float* __restrict__ Wup0, const float* __restrict__ Wup1,
    const float* __restrict__ tpw,
    const float* __restrict__ Wl0, const float* __restrict__ Wl1,
    const float* __restrict__ Wl2,
    float* __restrict__ Mf)           // Mf[m][t][v], 7*128*128 fp32
{
    __shared__ float wl[128][128];
    __shared__ float wu[32][128];
    __shared__ float tw[128];

    const int bx  = blockIdx.x;
    const int m   = bx >> 2;     // path 0..6
    const int tq  = bx & 3;      // t-quarter
    const int tid = threadIdx.x;

    const int upsel[7] = {0,0,0,1,1,1,1};
    const int wlsel[7] = {0,1,2,1,0,2,1};
    const int uoff [7] = {0,0,0,128,128,128,256};

    const float* Wup = upsel[m] ? Wup1 : Wup0;
    const float* Wl  = (wlsel[m]==0) ? Wl0 : ((wlsel[m]==1) ? Wl1 : Wl2);
    Wl += uoff[m] * 128;

    for (int idx = tid; idx < 16384; idx += 256)
        wl[idx >> 7][idx & 127] = Wl[idx];
    for (int idx = tid; idx < 4096; idx += 256)
        wu[idx >> 7][idx & 127] = Wup[(tq*32 + (idx >> 7))*128 + (idx & 127)];
    if (tid < 128) tw[tid] = tpw[m*128 + tid];
    __syncthreads();

    for (int oi = 0; oi < 16; ++oi) {
        int idx = tid + oi*256;           // 0..4095
        int tl  = idx >> 7;               // local t 0..31
        int v   = idx & 127;
        float acc = 0.f;
        #pragma unroll 4
        for (int u = 0; u < 128; ++u)
            acc += wu[tl][u] * tw[u] * wl[u][v];
        acc *= 0.08838834764831845f;      // 1/sqrt(128)
        Mf[(size_t)((m*128 + tq*32 + tl)*128 + v)] = acc;
    }
}

// ------------------------- kernel 2: fused fp32 main ------------------------
__device__ __forceinline__ void ld8(const float* __restrict__ p, float* d) {
    float4 a = *(const float4*)p;
    float4 b = *(const float4*)(p + 4);
    d[0]=a.x; d[1]=a.y; d[2]=a.z; d[3]=a.w;
    d[4]=b.x; d[5]=b.y; d[6]=b.z; d[7]=b.w;
}

__global__ __launch_bounds__(256) void fused_fp32(
    const float* __restrict__ nf, const float* __restrict__ mfeat,
    const float* __restrict__ Mf, float* __restrict__ out)
{
    __shared__ float sL[16][128];        // 8 KB
    __shared__ float vL[3][16][128];     // 24 KB
    __shared__ float mfl[16][12];

    const int tid = threadIdx.x;
    const int n0  = blockIdx.x * 16;
    const size_t gbase = (size_t)n0 * 512;

    // stage node_feats, de-interleaving the vector part (stride 3)
    for (int i = tid; i < 8192; i += 256) {
        float x = nf[gbase + i];
        int n = i >> 9, c = i & 511;
        if (c < 128) sL[n][c] = x;
        else { int d = c - 128; vL[d % 3][n][d / 3] = x; }
    }
    if (tid < 144) {
        int n = tid / 9, j = tid - n*9;
        mfl[n][j] = mfeat[(size_t)(n0 + n)*9 + j];
    }
    __syncthreads();

    const int n  = tid >> 4;             // local node 0..15
    const int v0 = (tid & 15) * 8;       // 8 v-columns per thread

    const float K0  = 0.04419417382415922f;   // (1/sqrt2)/16
    const float K1  = 0.029462782549439476f;  // 1/(24*sqrt2)
    const float K2  = 0.04419417382415922f;
    const float IS3 = 0.5773502691896258f;
    const float IS5 = 0.4472135954999579f;
    const float V1  = 0.31622776601683794f;   // 1/sqrt(10)
    const float W1  = 0.18257418583505536f;   // 1/sqrt(30)

    const float f0  = mfl[n][0];
    const float f1a = mfl[n][1], f1b = mfl[n][2], f1c = mfl[n][3];
    const float f20 = mfl[n][4], f21 = mfl[n][5], f22 = mfl[n][6];
    const float f23 = mfl[n][7], f24 = mfl[n][8];

    float* obase = out + (size_t)(n0 + n)*1152 + (size_t)v0*9;

    // =================== phase 0 : P0, Q4 -> j=0 ===================
    {
        float P0[8] = {0,0,0,0,0,0,0,0};
        float Q4[3][8] = {{0}};
        const float* M0p = Mf + 0*16384 + v0;
        const float* M4p = Mf + 4*16384 + v0;
        for (int k = 0; k < 128; ++k) {
            float sk = sL[n][k];
            float a0 = vL[0][n][k], a1 = vL[1][n][k], a2 = vL[2][n][k];
            float m0[8], m4[8];
            ld8(M0p + k*128, m0);
            ld8(M4p + k*128, m4);
            #pragma unroll
            for (int j = 0; j < 8; ++j) {
                P0[j]    += sk * m0[j];
                Q4[0][j] += a0 * m4[j];
                Q4[1][j] += a1 * m4[j];
                Q4[2][j] += a2 * m4[j];
            }
        }
        #pragma unroll
        for (int j = 0; j < 8; ++j) {
            float val = K0*( f0*P0[j] + IS3*(f1a*Q4[0][j] + f1b*Q4[1][j] + f1c*Q4[2][j]) );
            obase[j*9 + 0] = val;
        }
    }

    // =================== phase 1 : P1, Q3, Q6 -> j=1..3 ===================
    {
        float P1[8] = {0,0,0,0,0,0,0,0};
        float Q3[3][8] = {{0}};
        float Q6[3][8] = {{0}};
        const float* M1p = Mf + 1*16384 + v0;
        const float* M3p = Mf + 3*16384 + v0;
        const float* M6p = Mf + 6*16384 + v0;
        for (int k = 0; k < 128; ++k) {
            float sk = sL[n][k];
            float a0 = vL[0][n][k], a1 = vL[1][n][k], a2 = vL[2][n][k];
            float m1[8], m3[8], m6[8];
            ld8(M1p + k*128, m1);
            ld8(M3p + k*128, m3);
            ld8(M6p + k*128, m6);
            #pragma unroll
            for (int j = 0; j < 8; ++j) {
                P1[j]    += sk * m1[j];
                Q3[0][j] += a0 * m3[j];
                Q3[1][j] += a1 * m3[j];
                Q3[2][j] += a2 * m3[j];
                Q6[0][j] += a0 * m6[j];
                Q6[1][j] += a1 * m6[j];
                Q6[2][j] += a2 * m6[j];
            }
        }
        // g6[a][c] = sum_b C112[a,c,b] f2[b]
        float g600 = -W1*f22 - V1*f24, g601 = V1*f21,      g602 = V1*f20;
        float g610 =  V1*f21,          g611 = 2.f*W1*f22,  g612 = V1*f23;
        float g620 =  V1*f20,          g621 = V1*f23,      g622 = -W1*f22 + V1*f24;
        #pragma unroll
        for (int j = 0; j < 8; ++j) {
            float q30 = Q3[0][j], q31 = Q3[1][j], q32 = Q3[2][j];
            float q60 = Q6[0][j], q61 = Q6[1][j], q62 = Q6[2][j];
            float p   = P1[j];
            obase[j*9 + 1] = K1*( IS3*(f1a*p + f0*q30) + g600*q60 + g610*q61 + g620*q62 );
            obase[j*9 + 2] = K1*( IS3*(f1b*p + f0*q31) + g601*q60 + g611*q61 + g621*q62 );
            obase[j*9 + 3] = K1*( IS3*(f1c*p + f0*q32) + g602*q60 + g612*q61 + g622*q62 );
        }
    }

    // =================== phase 2 : P2, Q5 -> j=4..8 ===================
    {
        float P2[8] = {0,0,0,0,0,0,0,0};
        float Q5[3][8] = {{0}};
        const float* M2p = Mf + 2*16384 + v0;
        const float* M5p = Mf + 5*16384 + v0;
        for (int k = 0; k < 128; ++k) {
            float sk = sL[n][k];
            float a0 = vL[0][n][k], a1 = vL[1][n][k], a2 = vL[2][n][k];
            float m2[8], m5[8];
            ld8(M2p + k*128, m2);
            ld8(M5p + k*128, m5);
            #pragma unroll
            for (int j = 0; j < 8; ++j) {
                P2[j]    += sk * m2[j];
                Q5[0][j] += a0 * m5[j];
                Q5[1][j] += a1 * m5[j];
                Q5[2][j] += a2 * m5[j];
            }
        }
        #pragma unroll
        for (int j = 0; j < 8; ++j) {
            float p   = P2[j];
            float q50 = Q5[0][j], q51 = Q5[1][j], q52 = Q5[2][j];
            obase[j*9 + 4] = K2*( IS5*f20*p + V1*f1c*q50                   + V1*f1a*q52 );
            obase[j*9 + 5] = K2*( IS5*f21*p + V1*f1b*q50 + V1*f1a*q51 );
            obase[j*9 + 6] = K2*( IS5*f22*p - W1*f1a*q50 + 2.f*W1*f1b*q51 - W1*f1c*q52 );
            obase[j*9 + 7] = K2*( IS5*f23*p              + V1*f1c*q51     + V1*f1b*q52 );
            obase[j*9 + 8] = K2*( IS5*f24*p - V1*f1a*q50                   + V1*f1c*q52 );
        }
    }
}

// ------------------------------ launcher ------------------------------------
extern "C" void kernel_launch(void* const* d_in, const int* in_sizes, int n_in,
                              void* d_out, int out_size, void* d_ws, size_t ws_size,
                              hipStream_t stream) {
    const float* nf   = (const float*)d_in[0];
    const float* mf   = (const float*)d_in[1];
    const float* Wup0 = (const float*)d_in[2];
    const float* Wup1 = (const float*)d_in[3];
    const float* tpw  = (const float*)d_in[4];
    const float* Wl0  = (const float*)d_in[5];
    const float* Wl1  = (const float*)d_in[6];
    const float* Wl2  = (const float*)d_in[7];
    float* out = (float*)d_out;
    float* Mf  = (float*)d_ws;                 // 7*128*128 fp32 = 458,752 B

    const int N = in_sizes[0] / 512;           // 65536 nodes
    precompute_Mf<<<28, 256, 0, stream>>>(Wup0, Wup1, tpw, Wl0, Wl1, Wl2, Mf);
    fused_fp32<<<N / 16, 256, 0, stream>>>(nf, mf, Mf, out);
}